// Round 15
// baseline (19131.100 us; speedup 1.0000x reference)
//
#include <hip/hip_runtime.h>
#include <hip/hip_bf16.h>

#define SEQ_LEN 256
#define NB 64
#define NV 10000
#define NVP 10048
#define ND 1024
#define NBLK 256

typedef unsigned int u32;
typedef unsigned short u16;
typedef u32 u32x4 __attribute__((ext_vector_type(4)));
typedef short s16x8 __attribute__((ext_vector_type(8)));
typedef float f32x4 __attribute__((ext_vector_type(4)));

__device__ __forceinline__ float sigf(float z) { return 1.f / (1.f + expf(-z)); }

__device__ __forceinline__ float bflo(u32 u) {
  union { u32 i; float f; } v; v.i = u << 16; return v.f;
}
__device__ __forceinline__ float bfhi(u32 u) {
  union { u32 i; float f; } v; v.i = u & 0xffff0000u; return v.f;
}
__device__ __forceinline__ u16 f2bf(float f) {   // RNE
  u32 u = __float_as_uint(f);
  u32 r = u + 0x7FFFu + ((u >> 16) & 1u);
  return (u16)(r >> 16);
}

// sc1 store: write-through to L3, never dirties L2.
__device__ __forceinline__ void st_uc1(u32* p, u32 v) {
  asm volatile("global_store_dword %0, %1, off sc1" :: "v"(p), "v"(v) : "memory");
}
__device__ __forceinline__ s16x8 as_frag(u32x4 v) {
  union { u32x4 u; s16x8 s; } c; c.u = v; return c.s;
}

__device__ __forceinline__ float dot8_f32(const float* hv, const float* wp, float acc) {
  float4 w0 = *(const float4*)wp;
  float4 w1 = *(const float4*)(wp + 4);
  acc += hv[0] * w0.x; acc += hv[1] * w0.y; acc += hv[2] * w0.z; acc += hv[3] * w0.w;
  acc += hv[4] * w1.x; acc += hv[5] * w1.y; acc += hv[6] * w1.z; acc += hv[7] * w1.w;
  return acc;
}

// ---- diagnostic flood (f32 out) ----
__global__ void floodk(float* out, float val, unsigned long long n) {
  unsigned long long i = (unsigned long long)blockIdx.x * 256 + threadIdx.x;
  if (i < n) out[i] = val;
}

// ---- init: states feature-major f32 + batch-major bf16; zero barrier mem ----
__global__ void init_state(const float* __restrict__ h0, const float* __restrict__ c0,
                           float* __restrict__ cS, u16* __restrict__ hx16, u32* bar) {
  int i = blockIdx.x * 256 + threadIdx.x;   // 0..65535
  int k = i >> 6, b = i & 63;
  cS[i] = c0[b * ND + k];
  hx16[b * ND + k] = f2bf(h0[b * ND + k]);
  if (i < NBLK * 16) bar[i] = 0u;           // covers xcnt (8x32) + xflag (8)
}

// ---- decw f32 -> bf16, padded to NVP rows ----
__global__ void cvt_dec(const float* __restrict__ decw, u16* __restrict__ Wb) {
  size_t i = (size_t)blockIdx.x * 256 + threadIdx.x;
  size_t base = i * 8;
  if (base >= (size_t)NVP * ND) return;
  size_t row = base >> 10;
  ushort4 o0, o1;
  if (row < NV) {
    float4 v0 = *(const float4*)(decw + base);
    float4 v1 = *(const float4*)(decw + base + 4);
    o0 = make_ushort4(f2bf(v0.x), f2bf(v0.y), f2bf(v0.z), f2bf(v0.w));
    o1 = make_ushort4(f2bf(v1.x), f2bf(v1.y), f2bf(v1.z), f2bf(v1.w));
  } else {
    o0 = make_ushort4(0, 0, 0, 0); o1 = o0;
  }
  *(ushort4*)(Wb + base) = o0;
  *(ushort4*)(Wb + base + 4) = o1;
}

// ================= persistent fused sequence kernel (MFMA) =================
// Hierarchical barrier: 8 group counters (atomicAdd, parallel lines); the
// 32nd arriver of each group KNOWS from the returned old value and release-
// stores the group flag; all blocks poll ONE 32B line of 8 flags (single
// load per iteration). One acquire (buffer_inv) per block per phase.

__device__ __forceinline__ void fbar(u32* bar, u32 want) {
  asm volatile("s_waitcnt vmcnt(0)" ::: "memory");   // data stores reached L3
  __syncthreads();
  const int tid = threadIdx.x;
  u32* xcnt  = bar;                                  // [8] stride 32 u32 (128B)
  u32* xflag = bar + 2048;                           // [8] contiguous (one line)
  if (tid == 0) {
    const int g = blockIdx.x & 7;
    u32 old = __hip_atomic_fetch_add(xcnt + g * 32, 1u,
                                     __ATOMIC_ACQ_REL, __HIP_MEMORY_SCOPE_AGENT);
    if (old == want * 32u - 1u)                      // last of my 32-block group
      __hip_atomic_store(xflag + g, want,
                         __ATOMIC_RELEASE, __HIP_MEMORY_SCOPE_AGENT);
  }
  if (tid < 64) {
    for (;;) {
      u32 f = want;
      if (tid < 8)
        f = __hip_atomic_load(xflag + tid, __ATOMIC_RELAXED, __HIP_MEMORY_SCOPE_AGENT);
      if (__all((int)(f >= want))) break;
      __builtin_amdgcn_s_sleep(1);
    }
    // acquire fence: emits buffer_inv (invalidate vL1+L2) once per block
    (void)__hip_atomic_load(xflag, __ATOMIC_ACQUIRE, __HIP_MEMORY_SCOPE_AGENT);
  }
  __syncthreads();
}

// mog: out cols c0..c0+3 = 2*sig(act.W + b) * mult. rowbase = phase*4 in wAll.
template<bool EMB>
__device__ __forceinline__ void mogP(
    const u32* __restrict__ actU, const u16* wAll, int rowbase, const float* bL,
    const float* __restrict__ emb, const int* __restrict__ tok,
    const u32* __restrict__ multU, u32* __restrict__ outU,
    float* red, float* vals2, float* vals)
{
  const int tid = threadIdx.x;
  const int wv = tid >> 6, lane = tid & 63;
  const int c0 = blockIdx.x * 4;
  const int kb = wv * 128;
  const int lm = lane & 15, lh = lane >> 4;
  const u32* ap = actU + (size_t)lm * 512 + (kb >> 1) + lh * 4;
  const int g = rowbase + lm;
  const int swz = (g & 7) << 3;

  u32x4 A[4][4];
#pragma unroll
  for (int m = 0; m < 4; ++m)
#pragma unroll
    for (int ks = 0; ks < 4; ++ks)
      A[m][ks] = *(const u32x4*)(ap + m * 8192 + ks * 16);
  s16x8 bf[4];
#pragma unroll
  for (int ks = 0; ks < 4; ++ks)
    bf[ks] = *(const s16x8*)(wAll + g * 1024 + ((kb + ks * 32 + lh * 8) ^ swz));

  f32x4 acc[4];
#pragma unroll
  for (int m = 0; m < 4; ++m) { acc[m] = (f32x4){0.f,0.f,0.f,0.f}; }
#pragma unroll
  for (int ks = 0; ks < 4; ++ks)
#pragma unroll
    for (int m = 0; m < 4; ++m)
      acc[m] = __builtin_amdgcn_mfma_f32_16x16x32_bf16(as_frag(A[m][ks]), bf[ks], acc[m], 0, 0, 0);

#pragma unroll
  for (int m = 0; m < 4; ++m)
#pragma unroll
    for (int r = 0; r < 4; ++r)
      red[wv * 1024 + (m * 4 + r) * 64 + lane] = acc[m][r];
  __syncthreads();
  {
    float s0 = 0.f, s1 = 0.f;
#pragma unroll
    for (int w = 0; w < 8; ++w) { s0 += red[w * 1024 + tid]; s1 += red[w * 1024 + 512 + tid]; }
    vals2[tid] = s0; vals2[512 + tid] = s1;
  }
  __syncthreads();

  if (tid < 256) {
    const int c = tid >> 6, b = tid & 63;
    const int i = ((b >> 4) << 2) | (b & 3);
    const int l = (((b >> 2) & 3) << 4) | c;
    float z = vals2[i * 64 + l] + bL[c];
    float g2 = 2.f * sigf(z);
    float m;
    if (EMB) {
      m = emb[(size_t)tok[b] * ND + (c0 + c)];
    } else {
      u32 mu = multU[(size_t)b * 512 + ((c0 + c) >> 1)];
      m = (c & 1) ? bfhi(mu) : bflo(mu);
    }
    vals[c * 64 + b] = g2 * m;
  }
  __syncthreads();

  if (tid < 128) {
    const int cp = tid >> 6, b = tid & 63;
    float lo = vals[(2 * cp) * 64 + b];
    float hi = vals[(2 * cp + 1) * 64 + b];
    u32 pk = (u32)f2bf(lo) | ((u32)f2bf(hi) << 16);
    st_uc1(outU + (size_t)b * 512 + (c0 >> 1) + cp, pk);
  }
}

// gates: rows n = jj*4+g (16 per block). waves 0-3 x-half, 4-7 h-half.
__device__ __forceinline__ void gatesP(
    const u32* __restrict__ xU, const u32* __restrict__ hU,
    const u16* wAll, const float* bG, float& creg,
    u32* __restrict__ hBrow, u32* __restrict__ hxU, float* __restrict__ hFw,
    float* red, float* vals2, float* vals)
{
  const int tid = threadIdx.x;
  const int wv = tid >> 6, lane = tid & 63;
  const int j0 = blockIdx.x * 4;
  const int half = wv >> 2, kq = wv & 3;
  const int kb = kq * 256;
  const int lm = lane & 15, lh = lane >> 4;
  const u32* ap = (half ? hU : xU) + (size_t)lm * 512 + (kb >> 1) + lh * 4;
  const int g = 16 + half * 16 + lm;
  const int swz = (g & 7) << 3;

  u32x4 A[4][8];
#pragma unroll
  for (int m = 0; m < 4; ++m)
#pragma unroll
    for (int ks = 0; ks < 8; ++ks)
      A[m][ks] = *(const u32x4*)(ap + m * 8192 + ks * 16);
  s16x8 bf[8];
#pragma unroll
  for (int ks = 0; ks < 8; ++ks)
    bf[ks] = *(const s16x8*)(wAll + g * 1024 + ((kb + ks * 32 + lh * 8) ^ swz));

  f32x4 acc[4];
#pragma unroll
  for (int m = 0; m < 4; ++m) { acc[m] = (f32x4){0.f,0.f,0.f,0.f}; }
#pragma unroll
  for (int ks = 0; ks < 8; ++ks)
#pragma unroll
    for (int m = 0; m < 4; ++m)
      acc[m] = __builtin_amdgcn_mfma_f32_16x16x32_bf16(as_frag(A[m][ks]), bf[ks], acc[m], 0, 0, 0);

#pragma unroll
  for (int m = 0; m < 4; ++m)
#pragma unroll
    for (int r = 0; r < 4; ++r)
      red[wv * 1024 + (m * 4 + r) * 64 + lane] = acc[m][r];
  __syncthreads();
  {
    float s0 = 0.f, s1 = 0.f;
#pragma unroll
    for (int w = 0; w < 8; ++w) { s0 += red[w * 1024 + tid]; s1 += red[w * 1024 + 512 + tid]; }
    vals2[tid] = s0; vals2[512 + tid] = s1;
  }
  __syncthreads();

  if (tid < 256) {
    const int jj = tid >> 6, b = tid & 63;
    const int i = ((b >> 4) << 2) | (b & 3);
    const int lbase = (((b >> 2) & 3) << 4);
    float pre[4];
#pragma unroll
    for (int gg = 0; gg < 4; ++gg) {
      const int n = jj * 4 + gg;
      pre[gg] = vals2[i * 64 + (lbase | n)] + bG[n];
    }
    float iv = sigf(pre[0]), fv = sigf(pre[1]);
    float gv = tanhf(pre[2]), ov = sigf(pre[3]);
    float cn = fv * creg + iv * gv;
    creg = cn;
    float hn = ov * tanhf(cn);
    vals[jj * 64 + b] = hn;
    if (hFw) st_uc1((u32*)(hFw + (size_t)(j0 + jj) * NB + b), __float_as_uint(hn));
  }
  __syncthreads();

  if (tid < 128) {
    const int cp = tid >> 6, b = tid & 63;
    float lo = vals[(2 * cp) * 64 + b];
    float hi = vals[(2 * cp + 1) * 64 + b];
    u32 pk = (u32)f2bf(lo) | ((u32)f2bf(hi) << 16);
    st_uc1(hxU + (size_t)b * 512 + (blockIdx.x * 2) + cp, pk);
    st_uc1(hBrow + (size_t)b * 512 + (blockIdx.x * 2) + cp, pk);
  }
}

__global__ __launch_bounds__(512) void seq_kernel(
    const int* __restrict__ tokens, const float* __restrict__ emb,
    const float* __restrict__ qw, const float* __restrict__ qb,
    const float* __restrict__ rw, const float* __restrict__ rb,
    const float* __restrict__ wih, const float* __restrict__ whh,
    const float* __restrict__ bih, const float* __restrict__ bhh,
    u32* __restrict__ hxU, u32* __restrict__ xAU, u32* __restrict__ h1U,
    u32* __restrict__ xBU, u32* __restrict__ h3U,
    float* __restrict__ cS, u32* __restrict__ hB, float* __restrict__ hF,
    u32* bar)
{
  __shared__ u16 wAll[48 * 1024];        // 96 KB
  __shared__ float red[8 * 1024];        // 32 KB
  __shared__ float vals2[1024];
  __shared__ float vals[256];
  __shared__ float bMog[4][4];
  __shared__ float bGs[16];

  const int tid = threadIdx.x;
  const int c0 = blockIdx.x * 4;
  const size_t DH = (size_t)ND * ND;

  {
    const float* msrc[4] = {qw, rw, qw + DH, rw + DH};
#pragma unroll
    for (int m = 0; m < 4; ++m)
      for (int c = 0; c < 4; ++c) {
        const int g = m * 4 + c;
        const float* src = msrc[m] + (size_t)(c0 + c) * ND;
        u16* dst = wAll + g * 1024;
        const int swz = (g & 7) << 3;
        for (int k = tid; k < ND; k += 512) dst[k ^ swz] = f2bf(src[k]);
      }
#pragma unroll
    for (int m = 0; m < 2; ++m) {
      const float* W = m ? whh : wih;
      for (int r = 0; r < 16; ++r) {
        const int g = 16 + m * 16 + r;
        const float* src = W + ((size_t)(r & 3) * ND + c0 + (r >> 2)) * ND;
        u16* dst = wAll + g * 1024;
        const int swz = (g & 7) << 3;
        for (int k = tid; k < ND; k += 512) dst[k ^ swz] = f2bf(src[k]);
      }
    }
    if (tid < 16) {
      int p = tid >> 2, c = tid & 3;
      const float* bs = (p == 0) ? qb : (p == 1) ? rb : (p == 2) ? qb + ND : rb + ND;
      bMog[p][c] = bs[c0 + c];
    }
    if (tid >= 16 && tid < 32) {
      int r = tid - 16;
      int jj = r >> 2, g = r & 3;
      bGs[r] = bih[g * ND + c0 + jj] + bhh[g * ND + c0 + jj];
    }
  }
  float creg = 0.f;
  if (tid < 256) creg = cS[(size_t)(c0 + (tid >> 6)) * NB + (tid & 63)];
  __syncthreads();

  u32 want = 0;
  for (int t = 0; t < SEQ_LEN; ++t) {
    const int* tok = tokens + (size_t)t * NB;
    u32* hBrow = hB + (size_t)t * 32768;
    float* hFw = (t == SEQ_LEN - 1) ? hF : nullptr;
    mogP<true >(hxU, wAll, 0,  bMog[0], emb, tok, nullptr, xAU, red, vals2, vals); fbar(bar, ++want);
    mogP<false>(xAU, wAll, 4,  bMog[1], nullptr, nullptr, hxU, h1U, red, vals2, vals); fbar(bar, ++want);
    mogP<false>(h1U, wAll, 8,  bMog[2], nullptr, nullptr, xAU, xBU, red, vals2, vals); fbar(bar, ++want);
    mogP<false>(xBU, wAll, 12, bMog[3], nullptr, nullptr, h1U, h3U, red, vals2, vals); fbar(bar, ++want);
    gatesP(xBU, h3U, wAll, bGs, creg, hBrow, hxU, hFw, red, vals2, vals);              fbar(bar, ++want);
  }
  if (tid < 256) cS[(size_t)(c0 + (tid >> 6)) * NB + (tid & 63)] = creg;
}

// ---- MFMA decode: out[t][b][n] = h_bf[t] . decw_bf[n] + decb[n] ----
__global__ __launch_bounds__(256) void decode_mfma(
    const u32* __restrict__ hB,    // [t][b][512] u32 (bf16 pairs)
    const u16* __restrict__ Wb,    // [NVP][1024] bf16
    const float* __restrict__ bias,
    float* __restrict__ out)       // [t][b][NV]
{
  int bid = blockIdx.x;
  bid = (bid & 7) * (NBLK * 157 / 8) + (bid >> 3);   // XCD swizzle
  const int mt = bid / 157;
  const int nt = bid % 157;
  const int tid = threadIdx.x;
  const int wv = tid >> 6, lane = tid & 63;
  const int lm = lane & 15, lh = lane >> 4;
  const int n = nt * 64 + wv * 16 + lm;
  const u16* bp = Wb + (size_t)n * 1024 + lh * 8;
  const u32* ap = hB + (size_t)mt * 32768 + (size_t)lm * 512 + lh * 4;

  f32x4 acc[4];
#pragma unroll
  for (int m = 0; m < 4; ++m) acc[m] = (f32x4){0.f, 0.f, 0.f, 0.f};

#pragma unroll 4
  for (int ks = 0; ks < 32; ++ks) {
    s16x8 bf = *(const s16x8*)(bp + ks * 32);
#pragma unroll
    for (int m = 0; m < 4; ++m) {
      u32x4 av = *(const u32x4*)(ap + m * 8192 + ks * 16);
      acc[m] = __builtin_amdgcn_mfma_f32_16x16x32_bf16(as_frag(av), bf, acc[m], 0, 0, 0);
    }
  }

  const float db = (n < NV) ? bias[n] : 0.f;
  float* orow = out + (size_t)mt * NB * NV + n;
  if (n < NV) {
#pragma unroll
    for (int m = 0; m < 4; ++m)
#pragma unroll
      for (int r = 0; r < 4; ++r) {
        const int b = m * 16 + lh * 4 + r;
        orow[(size_t)b * NV] = acc[m][r] + db;
      }
  }
}

__global__ void finalize(const float* __restrict__ hT, const float* __restrict__ cT,
                         float* __restrict__ out) {
  int i = blockIdx.x * 256 + threadIdx.x;
  int k = i >> 6, b = i & 63;
  size_t base = (size_t)SEQ_LEN * NB * NV;
  out[base + (size_t)b * ND + k] = hT[i];
  out[base + (size_t)NB * ND + (size_t)b * ND + k] = cT[i];
}

// ================= fallback multi-launch kernels (proven) =================

__global__ void init_state_fb(const float* __restrict__ h0, const float* __restrict__ c0,
                              float* __restrict__ hT, float* __restrict__ cT) {
  int i = blockIdx.x * 256 + threadIdx.x;
  int k = i >> 6, b = i & 63;
  hT[i] = h0[b * ND + k];
  cT[i] = c0[b * ND + k];
}

template<bool EMB>
__global__ __launch_bounds__(256) void mog_phase(
    const float* __restrict__ actT, const float* __restrict__ W,
    const float* __restrict__ bias, const float* __restrict__ multT,
    const float* __restrict__ emb, const int* __restrict__ tok,
    float* __restrict__ outT)
{
  const int tid = threadIdx.x;
  const int wv = tid >> 6;
  const int lane = tid & 63;
  const int c0 = blockIdx.x * 4;
  __shared__ float red[4][4][64];

  float acc[4] = {0.f, 0.f, 0.f, 0.f};
  const int kb = wv * 256;
  const float* ap = actT + (size_t)kb * NB + lane;

  for (int k = 0; k < 256; k += 8) {
    float hv[8];
#pragma unroll
    for (int q = 0; q < 8; ++q) hv[q] = ap[(k + q) * NB];
#pragma unroll
    for (int c = 0; c < 4; ++c)
      acc[c] = dot8_f32(hv, W + (size_t)(c0 + c) * ND + kb + k, acc[c]);
  }
#pragma unroll
  for (int c = 0; c < 4; ++c) red[wv][c][lane] = acc[c];
  __syncthreads();

  const int c = tid >> 6, b = tid & 63;
  float z = red[0][c][b] + red[1][c][b] + red[2][c][b] + red[3][c][b];
  z += bias[c0 + c];
  float g = 2.f * sigf(z);
  float m;
  if (EMB) m = emb[(size_t)tok[b] * ND + (c0 + c)];
  else     m = multT[(size_t)(c0 + c) * NB + b];
  outT[(size_t)(c0 + c) * NB + b] = g * m;
}

__global__ __launch_bounds__(256) void lstm_gates2(
    const float* __restrict__ xT, const float* __restrict__ hT,
    const float* __restrict__ Wih, const float* __restrict__ Whh,
    const float* __restrict__ bih, const float* __restrict__ bhh,
    float* __restrict__ cT, float* __restrict__ hOut)
{
  const int tid = threadIdx.x;
  const int wv = tid >> 6, lane = tid & 63;
  const int j0 = blockIdx.x * 2;
  __shared__ float red[4][16][64];
  float acc[16];
#pragma unroll
  for (int i = 0; i < 16; ++i) acc[i] = 0.f;
  const int kb = wv * 256;
  const float* xp = xT + (size_t)kb * NB + lane;
  const float* hp = hT + (size_t)kb * NB + lane;

  for (int k = 0; k < 256; k += 8) {
    float xv[8], hv[8];
#pragma unroll
    for (int q = 0; q < 8; ++q) { xv[q] = xp[(k + q) * NB]; hv[q] = hp[(k + q) * NB]; }
#pragma unroll
    for (int jj = 0; jj < 2; ++jj)
#pragma unroll
      for (int g = 0; g < 4; ++g) {
        const size_t row = (size_t)(g * ND + j0 + jj) * ND + kb + k;
        acc[jj * 8 + g]     = dot8_f32(xv, Wih + row, acc[jj * 8 + g]);
        acc[jj * 8 + 4 + g] = dot8_f32(hv, Whh + row, acc[jj * 8 + 4 + g]);
      }
  }
#pragma unroll
  for (int i = 0; i < 16; ++i) red[wv][i][lane] = acc[i];
  __syncthreads();

  if (tid < 128) {
    const int b = tid & 63, jj = tid >> 6;
    const int j = j0 + jj;
    float pre[4];
#pragma unroll
    for (int g = 0; g < 4; ++g) {
      float s = 0.f;
#pragma unroll
      for (int w = 0; w < 4; ++w) s += red[w][jj * 8 + g][b] + red[w][jj * 8 + 4 + g][b];
      pre[g] = s + bih[g * ND + j] + bhh[g * ND + j];
    }
    float iv = sigf(pre[0]), fv = sigf(pre[1]);
    float gv = tanhf(pre[2]), ov = sigf(pre[3]);
    float cn = fv * cT[(size_t)j * NB + b] + iv * gv;
    float hn = ov * tanhf(cn);
    cT[(size_t)j * NB + b] = cn;
    hOut[(size_t)j * NB + b] = hn;
  }
}

__global__ __launch_bounds__(256) void decode_k(
    const float* __restrict__ hT, const float* __restrict__ W,
    const float* __restrict__ decb, float* __restrict__ out)
{
  const int tid = threadIdx.x;
  const int wv = tid >> 6, lane = tid & 63;
  const int v0 = blockIdx.x * 4;
  __shared__ float red[4][4][64];
  float acc[4] = {0.f, 0.f, 0.f, 0.f};
  const int kb = wv * 256;
  const float* hp = hT + (size_t)kb * NB + lane;

  for (int k = 0; k < 256; k += 8) {
    float hv[8];
#pragma unroll
    for (int q = 0; q < 8; ++q) hv[q] = hp[(k + q) * NB];
#pragma unroll
    for (int c = 0; c < 4; ++c)
      acc[c] = dot8_f32(hv, W + (size_t)(v0 + c) * ND + kb + k, acc[c]);
  }
#pragma unroll
  for (int c = 0; c < 4; ++c) red[wv][c][lane] = acc[c];
  __syncthreads();

  const int c = tid >> 6, b = tid & 63;
  float z = red[0][c][b] + red[1][c][b] + red[2][c][b] + red[3][c][b];
  z += decb[v0 + c];
  out[(size_t)b * NV + v0 + c] = z;
}

extern "C" void kernel_launch(void* const* d_in, const int* in_sizes, int n_in,
                              void* d_out, int out_size, void* d_ws, size_t ws_size,
                              hipStream_t stream)
{
  float* out = (float*)d_out;
  const unsigned long long expect_out = (unsigned long long)SEQ_LEN * NB * NV + 2ull * NB * ND;

  auto flood = [&](float v) {
    unsigned long long n = (unsigned long long)out_size;
    unsigned int g = (unsigned int)((n + 255) / 256);
    floodk<<<g, 256, 0, stream>>>(out, v, n);
  };
  const int expect_sz[14] = {
    SEQ_LEN * NB, NV * ND, 2 * ND * ND, 2 * ND, 2 * ND * ND, 2 * ND,
    4 * ND * ND, 4 * ND * ND, 4 * ND, 4 * ND, NV * ND, NV, NB * ND, NB * ND };
  if (n_in != 14) { flood(1000.f); return; }
  for (int i = 0; i < 14; ++i)
    if (in_sizes[i] != expect_sz[i]) { flood(1100.f + 100.f * i); return; }
  if ((unsigned long long)out_size != expect_out) { flood(2500.f); return; }

  float* ws = (float*)d_ws;
  const size_t SB = (size_t)ND * NB;   // 65536
  if (ws_size < 7 * SB * sizeof(float)) { flood(2600.f); return; }

  const int*   tokens = (const int*)d_in[0];
  const float* emb  = (const float*)d_in[1];
  const float* qw   = (const float*)d_in[2];
  const float* qb   = (const float*)d_in[3];
  const float* rw   = (const float*)d_in[4];
  const float* rb   = (const float*)d_in[5];
  const float* wih  = (const float*)d_in[6];
  const float* whh  = (const float*)d_in[7];
  const float* bih  = (const float*)d_in[8];
  const float* bhh  = (const float*)d_in[9];
  const float* decw = (const float*)d_in[10];
  const float* decb = (const float*)d_in[11];
  const float* h0   = (const float*)d_in[12];
  const float* c0   = (const float*)d_in[13];

  // big layout: cS f32 | hF f32 | hB u32[256*32768] | decwB u16[NVP*1024] | ex | bar
  float* cS    = ws;
  float* hF    = ws + SB;
  u32*   hB    = (u32*)(ws + 2 * SB);
  u16*   decwB = (u16*)(hB + (size_t)SEQ_LEN * 32768);
  u32*   ex    = (u32*)(decwB + (size_t)NVP * ND);
  const size_t EXB = 64 * 512;
  u32* hxU = ex + 0 * EXB;
  u32* xAU = ex + 1 * EXB;
  u32* h1U = ex + 2 * EXB;
  u32* xBU = ex + 3 * EXB;
  u32* h3U = ex + 4 * EXB;
  u32* bar = ex + 5 * EXB;

  const size_t DH = (size_t)ND * ND;
  const size_t need = 2 * SB * sizeof(float)
                    + (size_t)SEQ_LEN * 32768 * sizeof(u32)
                    + (size_t)NVP * ND * sizeof(u16)
                    + (5 * EXB + NBLK * 16) * sizeof(u32);
  const bool big = ws_size >= need;

  if (big) {
    init_state<<<256, 256, 0, stream>>>(h0, c0, cS, (u16*)hxU, bar);
    cvt_dec<<<(NVP * ND / 8 + 255) / 256, 256, 0, stream>>>(decw, decwB);
    seq_kernel<<<NBLK, 512, 0, stream>>>(tokens, emb, qw, qb, rw, rb,
                                         wih, whh, bih, bhh,
                                         hxU, xAU, h1U, xBU, h3U,
                                         cS, hB, hF, bar);
    decode_mfma<<<NBLK * 157, 256, 0, stream>>>(hB, decwB, decb, out);
    finalize<<<256, 256, 0, stream>>>(hF, cS, out);
  } else {
    // fallback: proven multi-launch path
    float* xA = ws + 0 * SB;
    float* xB = ws + 1 * SB;
    float* h1 = ws + 2 * SB;
    float* h3 = ws + 3 * SB;
    float* cSf = ws + 4 * SB;
    float* hA = ws + 5 * SB;
    float* hBf = ws + 6 * SB;
    init_state_fb<<<256, 256, 0, stream>>>(h0, c0, hA, cSf);
    float* hc = hA;
    float* hn = hBf;
    for (int t = 0; t < SEQ_LEN; ++t) {
      const int* tk = tokens + (size_t)t * NB;
      mog_phase<true ><<<256, 256, 0, stream>>>(hc, qw, qb, nullptr, emb, tk, xA);
      mog_phase<false><<<256, 256, 0, stream>>>(xA, rw, rb, hc, nullptr, nullptr, h1);
      mog_phase<false><<<256, 256, 0, stream>>>(h1, qw + DH, qb + ND, xA, nullptr, nullptr, xB);
      mog_phase<false><<<256, 256, 0, stream>>>(xB, rw + DH, rb + ND, h1, nullptr, nullptr, h3);
      lstm_gates2<<<512, 256, 0, stream>>>(xB, h3, wih, whh, bih, bhh, cSf, hn);
      decode_k<<<2500, 256, 0, stream>>>(hn, decw, decb, out + (size_t)t * NB * NV);
      float* tmp = hc; hc = hn; hn = tmp;
    }
    finalize<<<256, 256, 0, stream>>>(hc, cSf, out);
  }
}

// Round 16
// 14085.263 us; speedup vs baseline: 1.3582x; 1.3582x over previous
//
#include <hip/hip_runtime.h>
#include <hip/hip_bf16.h>

#define SEQ_LEN 256
#define NB 64
#define NV 10000
#define NVP 10048
#define ND 1024
#define NBLK 256

typedef unsigned int u32;
typedef unsigned short u16;
typedef u32 u32x2 __attribute__((ext_vector_type(2)));
typedef u32 u32x4 __attribute__((ext_vector_type(4)));
typedef short s16x8 __attribute__((ext_vector_type(8)));
typedef float f32x4 __attribute__((ext_vector_type(4)));

__device__ __forceinline__ float sigf(float z) { return 1.f / (1.f + expf(-z)); }

__device__ __forceinline__ float bflo(u32 u) {
  union { u32 i; float f; } v; v.i = u << 16; return v.f;
}
__device__ __forceinline__ float bfhi(u32 u) {
  union { u32 i; float f; } v; v.i = u & 0xffff0000u; return v.f;
}
__device__ __forceinline__ u16 f2bf(float f) {   // RNE
  u32 u = __float_as_uint(f);
  u32 r = u + 0x7FFFu + ((u >> 16) & 1u);
  return (u16)(r >> 16);
}

// sc1 stores: write-through to L3, never dirty L2.
__device__ __forceinline__ void st_uc1(u32* p, u32 v) {
  asm volatile("global_store_dword %0, %1, off sc1" :: "v"(p), "v"(v) : "memory");
}
__device__ __forceinline__ void st_uc1x2(u32* p, u32 a, u32 b) {
  u32x2 v = {a, b};
  asm volatile("global_store_dwordx2 %0, %1, off sc1" :: "v"(p), "v"(v) : "memory");
}
__device__ __forceinline__ s16x8 as_frag(u32x4 v) {
  union { u32x4 u; s16x8 s; } c; c.u = v; return c.s;
}

__device__ __forceinline__ float dot8_f32(const float* hv, const float* wp, float acc) {
  float4 w0 = *(const float4*)wp;
  float4 w1 = *(const float4*)(wp + 4);
  acc += hv[0] * w0.x; acc += hv[1] * w0.y; acc += hv[2] * w0.z; acc += hv[3] * w0.w;
  acc += hv[4] * w1.x; acc += hv[5] * w1.y; acc += hv[6] * w1.z; acc += hv[7] * w1.w;
  return acc;
}

// ---- diagnostic flood (f32 out) ----
__global__ void floodk(float* out, float val, unsigned long long n) {
  unsigned long long i = (unsigned long long)blockIdx.x * 256 + threadIdx.x;
  if (i < n) out[i] = val;
}

// ---- init: states feature-major f32 + batch-major bf16; zero flags ----
__global__ void init_state(const float* __restrict__ h0, const float* __restrict__ c0,
                           float* __restrict__ cS, u16* __restrict__ hx16, u32* flags) {
  int i = blockIdx.x * 256 + threadIdx.x;   // 0..65535
  int k = i >> 6, b = i & 63;
  cS[i] = c0[b * ND + k];
  hx16[b * ND + k] = f2bf(h0[b * ND + k]);
  if (i < NBLK * 16) flags[i] = 0u;         // 64B-padded per-block flags
}

// ---- decw f32 -> bf16, padded to NVP rows ----
__global__ void cvt_dec(const float* __restrict__ decw, u16* __restrict__ Wb) {
  size_t i = (size_t)blockIdx.x * 256 + threadIdx.x;
  size_t base = i * 8;
  if (base >= (size_t)NVP * ND) return;
  size_t row = base >> 10;
  ushort4 o0, o1;
  if (row < NV) {
    float4 v0 = *(const float4*)(decw + base);
    float4 v1 = *(const float4*)(decw + base + 4);
    o0 = make_ushort4(f2bf(v0.x), f2bf(v0.y), f2bf(v0.z), f2bf(v0.w));
    o1 = make_ushort4(f2bf(v1.x), f2bf(v1.y), f2bf(v1.z), f2bf(v1.w));
  } else {
    o0 = make_ushort4(0, 0, 0, 0); o1 = o0;
  }
  *(ushort4*)(Wb + base) = o0;
  *(ushort4*)(Wb + base + 4) = o1;
}

// ================= persistent fused sequence kernel (MFMA) =================
// Round-14 flag-array barrier (proven fastest) with one change: the post-poll
// acquire is a direct buffer_inv sc1 (vL1+L2 invalidate) instead of an
// acquire-load -> saves one L3 round trip per phase.

__device__ __forceinline__ void fbar(u32* flags, u32 want) {
  asm volatile("s_waitcnt vmcnt(0)" ::: "memory");   // sc1 data stores at L3
  __syncthreads();
  const int tid = threadIdx.x;
  if (tid == 0)
    __hip_atomic_store(flags + (size_t)blockIdx.x * 16, want,
                       __ATOMIC_RELAXED, __HIP_MEMORY_SCOPE_AGENT);
  if (tid < 64) {
    for (;;) {
      int ok = 1;
#pragma unroll
      for (int i = 0; i < 4; ++i) {
        u32 f = __hip_atomic_load(flags + (size_t)(tid * 4 + i) * 16,
                                  __ATOMIC_RELAXED, __HIP_MEMORY_SCOPE_AGENT);
        ok &= (f >= want);
      }
      if (__all(ok)) break;
      __builtin_amdgcn_s_sleep(1);
    }
    asm volatile("buffer_inv sc1" ::: "memory");     // invalidate vL1 + L2
  }
  __syncthreads();
}

// mog: out cols c0..c0+3 = 2*sig(act.W + b) * mult. rowbase = phase*4 in wAll.
// Fused epilogue: 2 syncs; 64 threads pack+store dwordx2.
template<bool EMB>
__device__ __forceinline__ void mogP(
    const u32* __restrict__ actU, const u16* wAll, int rowbase, const float* bL,
    const float* __restrict__ emb, const int* __restrict__ tok,
    const u32* __restrict__ multU, u32* __restrict__ outU,
    float* red, float* vals2)
{
  const int tid = threadIdx.x;
  const int wv = tid >> 6, lane = tid & 63;
  const int c0 = blockIdx.x * 4;
  const int kb = wv * 128;
  const int lm = lane & 15, lh = lane >> 4;
  const u32* ap = actU + (size_t)lm * 512 + (kb >> 1) + lh * 4;
  const int g = rowbase + lm;
  const int swz = (g & 7) << 3;

  u32x4 A[4][4];
#pragma unroll
  for (int m = 0; m < 4; ++m)
#pragma unroll
    for (int ks = 0; ks < 4; ++ks)
      A[m][ks] = *(const u32x4*)(ap + m * 8192 + ks * 16);
  s16x8 bf[4];
#pragma unroll
  for (int ks = 0; ks < 4; ++ks)
    bf[ks] = *(const s16x8*)(wAll + g * 1024 + ((kb + ks * 32 + lh * 8) ^ swz));

  f32x4 acc[4];
#pragma unroll
  for (int m = 0; m < 4; ++m) { acc[m] = (f32x4){0.f,0.f,0.f,0.f}; }
#pragma unroll
  for (int ks = 0; ks < 4; ++ks)
#pragma unroll
    for (int m = 0; m < 4; ++m)
      acc[m] = __builtin_amdgcn_mfma_f32_16x16x32_bf16(as_frag(A[m][ks]), bf[ks], acc[m], 0, 0, 0);

#pragma unroll
  for (int m = 0; m < 4; ++m)
#pragma unroll
    for (int r = 0; r < 4; ++r)
      red[wv * 1024 + (m * 4 + r) * 64 + lane] = acc[m][r];
  __syncthreads();
  {
    float s0 = 0.f, s1 = 0.f;
#pragma unroll
    for (int w = 0; w < 8; ++w) { s0 += red[w * 1024 + tid]; s1 += red[w * 1024 + 512 + tid]; }
    vals2[tid] = s0; vals2[512 + tid] = s1;
  }
  __syncthreads();

  if (tid < 64) {
    const int b = tid;
    const int i = ((b >> 4) << 2) | (b & 3);
    const int lbase = (((b >> 2) & 3) << 4);
    float v[4];
    float4 ev;
    u32 mu0 = 0, mu1 = 0;
    if (EMB) {
      ev = *(const float4*)(emb + (size_t)tok[b] * ND + c0);
    } else {
      const u32* mp = multU + (size_t)b * 512 + (c0 >> 1);
      mu0 = mp[0]; mu1 = mp[1];
    }
#pragma unroll
    for (int c = 0; c < 4; ++c) {
      float z = vals2[i * 64 + (lbase | c)] + bL[c];
      float g2 = 2.f * sigf(z);
      float m;
      if (EMB) m = (&ev.x)[c];
      else { u32 mu = (c < 2) ? mu0 : mu1; m = (c & 1) ? bfhi(mu) : bflo(mu); }
      v[c] = g2 * m;
    }
    u32 pk0 = (u32)f2bf(v[0]) | ((u32)f2bf(v[1]) << 16);
    u32 pk1 = (u32)f2bf(v[2]) | ((u32)f2bf(v[3]) << 16);
    st_uc1x2(outU + (size_t)b * 512 + (c0 >> 1), pk0, pk1);
  }
}

// gates: rows n = jj*4+g (16 per block). waves 0-3 x-half, 4-7 h-half.
__device__ __forceinline__ void gatesP(
    const u32* __restrict__ xU, const u32* __restrict__ hU,
    const u16* wAll, const float* bG, float& creg,
    u32* __restrict__ hBrow, u32* __restrict__ hxU, float* __restrict__ hFw,
    float* red, float* vals2, float* vals)
{
  const int tid = threadIdx.x;
  const int wv = tid >> 6, lane = tid & 63;
  const int j0 = blockIdx.x * 4;
  const int half = wv >> 2, kq = wv & 3;
  const int kb = kq * 256;
  const int lm = lane & 15, lh = lane >> 4;
  const u32* ap = (half ? hU : xU) + (size_t)lm * 512 + (kb >> 1) + lh * 4;
  const int g = 16 + half * 16 + lm;
  const int swz = (g & 7) << 3;

  u32x4 A[4][8];
#pragma unroll
  for (int m = 0; m < 4; ++m)
#pragma unroll
    for (int ks = 0; ks < 8; ++ks)
      A[m][ks] = *(const u32x4*)(ap + m * 8192 + ks * 16);
  s16x8 bf[8];
#pragma unroll
  for (int ks = 0; ks < 8; ++ks)
    bf[ks] = *(const s16x8*)(wAll + g * 1024 + ((kb + ks * 32 + lh * 8) ^ swz));

  f32x4 acc[4];
#pragma unroll
  for (int m = 0; m < 4; ++m) { acc[m] = (f32x4){0.f,0.f,0.f,0.f}; }
#pragma unroll
  for (int ks = 0; ks < 8; ++ks)
#pragma unroll
    for (int m = 0; m < 4; ++m)
      acc[m] = __builtin_amdgcn_mfma_f32_16x16x32_bf16(as_frag(A[m][ks]), bf[ks], acc[m], 0, 0, 0);

#pragma unroll
  for (int m = 0; m < 4; ++m)
#pragma unroll
    for (int r = 0; r < 4; ++r)
      red[wv * 1024 + (m * 4 + r) * 64 + lane] = acc[m][r];
  __syncthreads();
  {
    float s0 = 0.f, s1 = 0.f;
#pragma unroll
    for (int w = 0; w < 8; ++w) { s0 += red[w * 1024 + tid]; s1 += red[w * 1024 + 512 + tid]; }
    vals2[tid] = s0; vals2[512 + tid] = s1;
  }
  __syncthreads();

  if (tid < 256) {
    const int jj = tid >> 6, b = tid & 63;
    const int i = ((b >> 4) << 2) | (b & 3);
    const int lbase = (((b >> 2) & 3) << 4);
    float pre[4];
#pragma unroll
    for (int gg = 0; gg < 4; ++gg) {
      const int n = jj * 4 + gg;
      pre[gg] = vals2[i * 64 + (lbase | n)] + bG[n];
    }
    float iv = sigf(pre[0]), fv = sigf(pre[1]);
    float gv = tanhf(pre[2]), ov = sigf(pre[3]);
    float cn = fv * creg + iv * gv;
    creg = cn;
    float hn = ov * tanhf(cn);
    vals[jj * 64 + b] = hn;
    if (hFw) st_uc1((u32*)(hFw + (size_t)(j0 + jj) * NB + b), __float_as_uint(hn));
  }
  __syncthreads();

  if (tid < 64) {
    const int b = tid;
    float v0 = vals[0 * 64 + b], v1 = vals[1 * 64 + b];
    float v2 = vals[2 * 64 + b], v3 = vals[3 * 64 + b];
    u32 pk0 = (u32)f2bf(v0) | ((u32)f2bf(v1) << 16);
    u32 pk1 = (u32)f2bf(v2) | ((u32)f2bf(v3) << 16);
    st_uc1x2(hxU + (size_t)b * 512 + blockIdx.x * 2, pk0, pk1);
    st_uc1x2(hBrow + (size_t)b * 512 + blockIdx.x * 2, pk0, pk1);
  }
}

__global__ __launch_bounds__(512) void seq_kernel(
    const int* __restrict__ tokens, const float* __restrict__ emb,
    const float* __restrict__ qw, const float* __restrict__ qb,
    const float* __restrict__ rw, const float* __restrict__ rb,
    const float* __restrict__ wih, const float* __restrict__ whh,
    const float* __restrict__ bih, const float* __restrict__ bhh,
    u32* __restrict__ hxU, u32* __restrict__ xAU, u32* __restrict__ h1U,
    u32* __restrict__ xBU, u32* __restrict__ h3U,
    float* __restrict__ cS, u32* __restrict__ hB, float* __restrict__ hF,
    u32* flags)
{
  __shared__ u16 wAll[48 * 1024];        // 96 KB
  __shared__ float red[8 * 1024];        // 32 KB
  __shared__ float vals2[1024];
  __shared__ float vals[256];
  __shared__ float bMog[4][4];
  __shared__ float bGs[16];

  const int tid = threadIdx.x;
  const int c0 = blockIdx.x * 4;
  const size_t DH = (size_t)ND * ND;

  {
    const float* msrc[4] = {qw, rw, qw + DH, rw + DH};
#pragma unroll
    for (int m = 0; m < 4; ++m)
      for (int c = 0; c < 4; ++c) {
        const int g = m * 4 + c;
        const float* src = msrc[m] + (size_t)(c0 + c) * ND;
        u16* dst = wAll + g * 1024;
        const int swz = (g & 7) << 3;
        for (int k = tid; k < ND; k += 512) dst[k ^ swz] = f2bf(src[k]);
      }
#pragma unroll
    for (int m = 0; m < 2; ++m) {
      const float* W = m ? whh : wih;
      for (int r = 0; r < 16; ++r) {
        const int g = 16 + m * 16 + r;
        const float* src = W + ((size_t)(r & 3) * ND + c0 + (r >> 2)) * ND;
        u16* dst = wAll + g * 1024;
        const int swz = (g & 7) << 3;
        for (int k = tid; k < ND; k += 512) dst[k ^ swz] = f2bf(src[k]);
      }
    }
    if (tid < 16) {
      int p = tid >> 2, c = tid & 3;
      const float* bs = (p == 0) ? qb : (p == 1) ? rb : (p == 2) ? qb + ND : rb + ND;
      bMog[p][c] = bs[c0 + c];
    }
    if (tid >= 16 && tid < 32) {
      int r = tid - 16;
      int jj = r >> 2, g = r & 3;
      bGs[r] = bih[g * ND + c0 + jj] + bhh[g * ND + c0 + jj];
    }
  }
  float creg = 0.f;
  if (tid < 256) creg = cS[(size_t)(c0 + (tid >> 6)) * NB + (tid & 63)];
  __syncthreads();

  u32 want = 0;
  for (int t = 0; t < SEQ_LEN; ++t) {
    const int* tok = tokens + (size_t)t * NB;
    u32* hBrow = hB + (size_t)t * 32768;
    float* hFw = (t == SEQ_LEN - 1) ? hF : nullptr;
    mogP<true >(hxU, wAll, 0,  bMog[0], emb, tok, nullptr, xAU, red, vals2); fbar(flags, ++want);
    mogP<false>(xAU, wAll, 4,  bMog[1], nullptr, nullptr, hxU, h1U, red, vals2); fbar(flags, ++want);
    mogP<false>(h1U, wAll, 8,  bMog[2], nullptr, nullptr, xAU, xBU, red, vals2); fbar(flags, ++want);
    mogP<false>(xBU, wAll, 12, bMog[3], nullptr, nullptr, h1U, h3U, red, vals2); fbar(flags, ++want);
    gatesP(xBU, h3U, wAll, bGs, creg, hBrow, hxU, hFw, red, vals2, vals);        fbar(flags, ++want);
  }
  if (tid < 256) cS[(size_t)(c0 + (tid >> 6)) * NB + (tid & 63)] = creg;
}

// ---- MFMA decode: out[t][b][n] = h_bf[t] . decw_bf[n] + decb[n] ----
__global__ __launch_bounds__(256) void decode_mfma(
    const u32* __restrict__ hB,    // [t][b][512] u32 (bf16 pairs)
    const u16* __restrict__ Wb,    // [NVP][1024] bf16
    const float* __restrict__ bias,
    float* __restrict__ out)       // [t][b][NV]
{
  int bid = blockIdx.x;
  bid = (bid & 7) * (NBLK * 157 / 8) + (bid >> 3);   // XCD swizzle
  const int mt = bid / 157;
  const int nt = bid % 157;
  const int tid = threadIdx.x;
  const int wv = tid >> 6, lane = tid & 63;
  const int lm = lane & 15, lh = lane >> 4;
  const int n = nt * 64 + wv * 16 + lm;
  const u16* bp = Wb + (size_t)n * 1024 + lh * 8;
  const u32* ap = hB + (size_t)mt * 32768 + (size_t)lm * 512 + lh * 4;

  f32x4 acc[4];
#pragma unroll
  for (int m = 0; m < 4; ++m) acc[m] = (f32x4){0.f, 0.f, 0.f, 0.f};

#pragma unroll 4
  for (int ks = 0; ks < 32; ++ks) {
    s16x8 bf = *(const s16x8*)(bp + ks * 32);
#pragma unroll
    for (int m = 0; m < 4; ++m) {
      u32x4 av = *(const u32x4*)(ap + m * 8192 + ks * 16);
      acc[m] = __builtin_amdgcn_mfma_f32_16x16x32_bf16(as_frag(av), bf, acc[m], 0, 0, 0);
    }
  }

  const float db = (n < NV) ? bias[n] : 0.f;
  float* orow = out + (size_t)mt * NB * NV + n;
  if (n < NV) {
#pragma unroll
    for (int m = 0; m < 4; ++m)
#pragma unroll
      for (int r = 0; r < 4; ++r) {
        const int b = m * 16 + lh * 4 + r;
        orow[(size_t)b * NV] = acc[m][r] + db;
      }
  }
}

__global__ void finalize(const float* __restrict__ hT, const float* __restrict__ cT,
                         float* __restrict__ out) {
  int i = blockIdx.x * 256 + threadIdx.x;
  int k = i >> 6, b = i & 63;
  size_t base = (size_t)SEQ_LEN * NB * NV;
  out[base + (size_t)b * ND + k] = hT[i];
  out[base + (size_t)NB * ND + (size_t)b * ND + k] = cT[i];
}

// ================= fallback multi-launch kernels (proven) =================

__global__ void init_state_fb(const float* __restrict__ h0, const float* __restrict__ c0,
                              float* __restrict__ hT, float* __restrict__ cT) {
  int i = blockIdx.x * 256 + threadIdx.x;
  int k = i >> 6, b = i & 63;
  hT[i] = h0[b * ND + k];
  cT[i] = c0[b * ND + k];
}

template<bool EMB>
__global__ __launch_bounds__(256) void mog_phase(
    const float* __restrict__ actT, const float* __restrict__ W,
    const float* __restrict__ bias, const float* __restrict__ multT,
    const float* __restrict__ emb, const int* __restrict__ tok,
    float* __restrict__ outT)
{
  const int tid = threadIdx.x;
  const int wv = tid >> 6;
  const int lane = tid & 63;
  const int c0 = blockIdx.x * 4;
  __shared__ float red[4][4][64];

  float acc[4] = {0.f, 0.f, 0.f, 0.f};
  const int kb = wv * 256;
  const float* ap = actT + (size_t)kb * NB + lane;

  for (int k = 0; k < 256; k += 8) {
    float hv[8];
#pragma unroll
    for (int q = 0; q < 8; ++q) hv[q] = ap[(k + q) * NB];
#pragma unroll
    for (int c = 0; c < 4; ++c)
      acc[c] = dot8_f32(hv, W + (size_t)(c0 + c) * ND + kb + k, acc[c]);
  }
#pragma unroll
  for (int c = 0; c < 4; ++c) red[wv][c][lane] = acc[c];
  __syncthreads();

  const int c = tid >> 6, b = tid & 63;
  float z = red[0][c][b] + red[1][c][b] + red[2][c][b] + red[3][c][b];
  z += bias[c0 + c];
  float g = 2.f * sigf(z);
  float m;
  if (EMB) m = emb[(size_t)tok[b] * ND + (c0 + c)];
  else     m = multT[(size_t)(c0 + c) * NB + b];
  outT[(size_t)(c0 + c) * NB + b] = g * m;
}

__global__ __launch_bounds__(256) void lstm_gates2(
    const float* __restrict__ xT, const float* __restrict__ hT,
    const float* __restrict__ Wih, const float* __restrict__ Whh,
    const float* __restrict__ bih, const float* __restrict__ bhh,
    float* __restrict__ cT, float* __restrict__ hOut)
{
  const int tid = threadIdx.x;
  const int wv = tid >> 6, lane = tid & 63;
  const int j0 = blockIdx.x * 2;
  __shared__ float red[4][16][64];
  float acc[16];
#pragma unroll
  for (int i = 0; i < 16; ++i) acc[i] = 0.f;
  const int kb = wv * 256;
  const float* xp = xT + (size_t)kb * NB + lane;
  const float* hp = hT + (size_t)kb * NB + lane;

  for (int k = 0; k < 256; k += 8) {
    float xv[8], hv[8];
#pragma unroll
    for (int q = 0; q < 8; ++q) { xv[q] = xp[(k + q) * NB]; hv[q] = hp[(k + q) * NB]; }
#pragma unroll
    for (int jj = 0; jj < 2; ++jj)
#pragma unroll
      for (int g = 0; g < 4; ++g) {
        const size_t row = (size_t)(g * ND + j0 + jj) * ND + kb + k;
        acc[jj * 8 + g]     = dot8_f32(xv, Wih + row, acc[jj * 8 + g]);
        acc[jj * 8 + 4 + g] = dot8_f32(hv, Whh + row, acc[jj * 8 + 4 + g]);
      }
  }
#pragma unroll
  for (int i = 0; i < 16; ++i) red[wv][i][lane] = acc[i];
  __syncthreads();

  if (tid < 128) {
    const int b = tid & 63, jj = tid >> 6;
    const int j = j0 + jj;
    float pre[4];
#pragma unroll
    for (int g = 0; g < 4; ++g) {
      float s = 0.f;
#pragma unroll
      for (int w = 0; w < 4; ++w) s += red[w][jj * 8 + g][b] + red[w][jj * 8 + 4 + g][b];
      pre[g] = s + bih[g * ND + j] + bhh[g * ND + j];
    }
    float iv = sigf(pre[0]), fv = sigf(pre[1]);
    float gv = tanhf(pre[2]), ov = sigf(pre[3]);
    float cn = fv * cT[(size_t)j * NB + b] + iv * gv;
    float hn = ov * tanhf(cn);
    cT[(size_t)j * NB + b] = cn;
    hOut[(size_t)j * NB + b] = hn;
  }
}

__global__ __launch_bounds__(256) void decode_k(
    const float* __restrict__ hT, const float* __restrict__ W,
    const float* __restrict__ decb, float* __restrict__ out)
{
  const int tid = threadIdx.x;
  const int wv = tid >> 6, lane = tid & 63;
  const int v0 = blockIdx.x * 4;
  __shared__ float red[4][4][64];
  float acc[4] = {0.f, 0.f, 0.f, 0.f};
  const int kb = wv * 256;
  const float* hp = hT + (size_t)kb * NB + lane;

  for (int k = 0; k < 256; k += 8) {
    float hv[8];
#pragma unroll
    for (int q = 0; q < 8; ++q) hv[q] = hp[(k + q) * NB];
#pragma unroll
    for (int c = 0; c < 4; ++c)
      acc[c] = dot8_f32(hv, W + (size_t)(v0 + c) * ND + kb + k, acc[c]);
  }
#pragma unroll
  for (int c = 0; c < 4; ++c) red[wv][c][lane] = acc[c];
  __syncthreads();

  const int c = tid >> 6, b = tid & 63;
  float z = red[0][c][b] + red[1][c][b] + red[2][c][b] + red[3][c][b];
  z += decb[v0 + c];
  out[(size_t)b * NV + v0 + c] = z;
}

extern "C" void kernel_launch(void* const* d_in, const int* in_sizes, int n_in,
                              void* d_out, int out_size, void* d_ws, size_t ws_size,
                              hipStream_t stream)
{
  float* out = (float*)d_out;
  const unsigned long long expect_out = (unsigned long long)SEQ_LEN * NB * NV + 2ull * NB * ND;

  auto flood = [&](float v) {
    unsigned long long n = (unsigned long long)out_size;
    unsigned int g = (unsigned int)((n + 255) / 256);
    floodk<<<g, 256, 0, stream>>>(out, v, n);
  };
  const int expect_sz[14] = {
    SEQ_LEN * NB, NV * ND, 2 * ND * ND, 2 * ND, 2 * ND * ND, 2 * ND,
    4 * ND * ND, 4 * ND * ND, 4 * ND, 4 * ND, NV * ND, NV, NB * ND, NB * ND };
  if (n_in != 14) { flood(1000.f); return; }
  for (int i = 0; i < 14; ++i)
    if (in_sizes[i] != expect_sz[i]) { flood(1100.f + 100.f * i); return; }
  if ((unsigned long long)out_size != expect_out) { flood(2500.f); return; }

  float* ws = (float*)d_ws;
  const size_t SB = (size_t)ND * NB;   // 65536
  if (ws_size < 7 * SB * sizeof(float)) { flood(2600.f); return; }

  const int*   tokens = (const int*)d_in[0];
  const float* emb  = (const float*)d_in[1];
  const float* qw   = (const float*)d_in[2];
  const float* qb   = (const float*)d_in[3];
  const float* rw   = (const float*)d_in[4];
  const float* rb   = (const float*)d_in[5];
  const float* wih  = (const float*)d_in[6];
  const float* whh  = (const float*)d_in[7];
  const float* bih  = (const float*)d_in[8];
  const float* bhh  = (const float*)d_in[9];
  const float* decw = (const float*)d_in[10];
  const float* decb = (const float*)d_in[11];
  const float* h0   = (const float*)d_in[12];
  const float* c0   = (const float*)d_in[13];

  // big layout: cS f32 | hF f32 | hB u32[256*32768] | decwB u16[NVP*1024] | ex | flags
  float* cS    = ws;
  float* hF    = ws + SB;
  u32*   hB    = (u32*)(ws + 2 * SB);
  u16*   decwB = (u16*)(hB + (size_t)SEQ_LEN * 32768);
  u32*   ex    = (u32*)(decwB + (size_t)NVP * ND);
  const size_t EXB = 64 * 512;
  u32* hxU = ex + 0 * EXB;
  u32* xAU = ex + 1 * EXB;
  u32* h1U = ex + 2 * EXB;
  u32* xBU = ex + 3 * EXB;
  u32* h3U = ex + 4 * EXB;
  u32* flags = ex + 5 * EXB;

  const size_t DH = (size_t)ND * ND;
  const size_t need = 2 * SB * sizeof(float)
                    + (size_t)SEQ_LEN * 32768 * sizeof(u32)
                    + (size_t)NVP * ND * sizeof(u16)
                    + (5 * EXB + NBLK * 16) * sizeof(u32);
  const bool big = ws_size >= need;

  if (big) {
    init_state<<<256, 256, 0, stream>>>(h0, c0, cS, (u16*)hxU, flags);
    cvt_dec<<<(NVP * ND / 8 + 255) / 256, 256, 0, stream>>>(decw, decwB);
    seq_kernel<<<NBLK, 512, 0, stream>>>(tokens, emb, qw, qb, rw, rb,
                                         wih, whh, bih, bhh,
                                         hxU, xAU, h1U, xBU, h3U,
                                         cS, hB, hF, flags);
    decode_mfma<<<NBLK * 157, 256, 0, stream>>>(hB, decwB, decb, out);
    finalize<<<256, 256, 0, stream>>>(hF, cS, out);
  } else {
    // fallback: proven multi-launch path
    float* xA = ws + 0 * SB;
    float* xB = ws + 1 * SB;
    float* h1 = ws + 2 * SB;
    float* h3 = ws + 3 * SB;
    float* cSf = ws + 4 * SB;
    float* hA = ws + 5 * SB;
    float* hBf = ws + 6 * SB;
    init_state_fb<<<256, 256, 0, stream>>>(h0, c0, hA, cSf);
    float* hc = hA;
    float* hn = hBf;
    for (int t = 0; t < SEQ_LEN; ++t) {
      const int* tk = tokens + (size_t)t * NB;
      mog_phase<true ><<<256, 256, 0, stream>>>(hc, qw, qb, nullptr, emb, tk, xA);
      mog_phase<false><<<256, 256, 0, stream>>>(xA, rw, rb, hc, nullptr, nullptr, h1);
      mog_phase<false><<<256, 256, 0, stream>>>(h1, qw + DH, qb + ND, xA, nullptr, nullptr, xB);
      mog_phase<false><<<256, 256, 0, stream>>>(xB, rw + DH, rb + ND, h1, nullptr, nullptr, h3);
      lstm_gates2<<<512, 256, 0, stream>>>(xB, h3, wih, whh, bih, bhh, cSf, hn);
      decode_k<<<2500, 256, 0, stream>>>(hn, decw, decb, out + (size_t)t * NB * NV);
      float* tmp = hc; hc = hn; hn = tmp;
    }
    finalize<<<256, 256, 0, stream>>>(hc, cSf, out);
  }
}